// Round 4
// baseline (2776.750 us; speedup 1.0000x reference)
//
#include <hip/hip_runtime.h>

#define NN 100000
#define EE 1600000
#define IN_DIM 128
#define HID 64
#define NH 4
#define DH 16
#define NL 3
#define OUT_DIM 64
#define SLOPE 0.2f
#define LN_EPS 1e-5f
#define RB 8

#define SCAN_CHUNK 1024
#define NBLK ((NN + SCAN_CHUNK - 1) / SCAN_CHUNK)   // 98

__device__ __forceinline__ float lrelu(float x) {
    return x > 0.f ? x : SLOPE * x;
}
__device__ __forceinline__ float bcast(float x, int lane) {
    return __int_as_float(__builtin_amdgcn_readlane(__float_as_int(x), lane));
}
__device__ __forceinline__ unsigned short f2bf(float x) {
    unsigned u = __float_as_uint(x);
    u += 0x7FFFu + ((u >> 16) & 1u);      // RNE
    return (unsigned short)(u >> 16);
}
__device__ __forceinline__ float bf2f(unsigned short b) {
    return __uint_as_float(((unsigned)b) << 16);
}

// h0 = X @ W_in + b_in   (N x 128) @ (128 x 64). 8 rows per wave, 32 rows/block.
__global__ void k_in_gemm(const float* __restrict__ X, const float* __restrict__ W,
                          const float* __restrict__ b, float* __restrict__ h) {
    __shared__ float4 WsT4[IN_DIM * HID / 4];   // 32 KB, transposed+swizzled
    float* WsT = (float*)WsT4;
    for (int idx = threadIdx.x; idx < IN_DIM * HID; idx += blockDim.x) {
        const int j = idx >> 7, k = idx & 127;
        const int p = (k >> 2) ^ (j & 15);
        WsT[j * IN_DIM + p * 4 + (k & 3)] = W[k * HID + j];
    }
    __syncthreads();
    const int j  = threadIdx.x & 63;
    const int vi = threadIdx.x >> 6;
    const float bj = b[j];
    const float* wrow = WsT + j * IN_DIM;
    const int sw = j & 15;
    const int v0 = blockIdx.x * (4 * RB) + vi * RB;   // NN == 32*3125, no tail
    float acc[RB];
#pragma unroll
    for (int r = 0; r < RB; ++r) acc[r] = bj;
    const float4* xr = (const float4*)(X + (size_t)v0 * IN_DIM);
#pragma unroll 8
    for (int c = 0; c < 32; ++c) {
        const float4 wv = *(const float4*)(wrow + ((c ^ sw) << 2));
#pragma unroll
        for (int r = 0; r < RB; ++r) {
            const float4 xv = xr[r * 32 + c];
            acc[r] += xv.x * wv.x + xv.y * wv.y + xv.z * wv.z + xv.w * wv.w;
        }
    }
#pragma unroll
    for (int r = 0; r < RB; ++r) h[(size_t)(v0 + r) * HID + j] = acc[r];
}

// z(bf16) = h @ W (64x64), plus el/er head reductions. 8 rows/wave.
__global__ void k_zgemm(const float* __restrict__ h, const float* __restrict__ W,
                        const float* __restrict__ al, const float* __restrict__ ar,
                        unsigned short* __restrict__ zb,
                        float* __restrict__ el, float* __restrict__ er) {
    __shared__ float4 WsT4[HID * HID / 4];      // 16 KB
    float* WsT = (float*)WsT4;
    for (int idx = threadIdx.x; idx < HID * HID; idx += blockDim.x) {
        const int j = idx >> 6, k = idx & 63;
        const int p = (k >> 2) ^ (j & 15);
        WsT[j * HID + p * 4 + (k & 3)] = W[k * HID + j];
    }
    __syncthreads();
    const int j  = threadIdx.x & 63;
    const int vi = threadIdx.x >> 6;
    const int head = j >> 4;
    const float alj = al[j];
    const float arj = ar[j];
    const float* wrow = WsT + j * HID;
    const int sw = j & 15;
    const int v0 = blockIdx.x * (4 * RB) + vi * RB;
    float acc[RB];
#pragma unroll
    for (int r = 0; r < RB; ++r) acc[r] = 0.f;
    const float4* hr = (const float4*)(h + (size_t)v0 * HID);
#pragma unroll
    for (int c = 0; c < 16; ++c) {
        const float4 wv = *(const float4*)(wrow + ((c ^ sw) << 2));
#pragma unroll
        for (int r = 0; r < RB; ++r) {
            const float4 hv = hr[r * 16 + c];
            acc[r] += hv.x * wv.x + hv.y * wv.y + hv.z * wv.z + hv.w * wv.w;
        }
    }
#pragma unroll
    for (int r = 0; r < RB; ++r) {
        zb[(size_t)(v0 + r) * HID + j] = f2bf(acc[r]);
        float pl = acc[r] * alj, pr = acc[r] * arj;
#pragma unroll
        for (int m = 8; m >= 1; m >>= 1) {
            pl += __shfl_xor(pl, m, 64);
            pr += __shfl_xor(pr, m, 64);
        }
        if ((j & 15) == 0) {
            el[(v0 + r) * NH + head] = pl;
            er[(v0 + r) * NH + head] = pr;
        }
    }
}

// ---------------- CSR build (once per launch) ----------------

__global__ void k_zero_deg(int* __restrict__ deg) {
    const int i = blockIdx.x * blockDim.x + threadIdx.x;
    if (i < NN) deg[i] = 0;
}

__global__ void k_hist(const int* __restrict__ dst, int* __restrict__ deg) {
    const int e = blockIdx.x * blockDim.x + threadIdx.x;
    if (e < EE) atomicAdd(&deg[dst[e]], 1);
}

__global__ void k_blocksum(const int* __restrict__ deg, int* __restrict__ bsum) {
    const int b = blockIdx.x, t = threadIdx.x;
    const int i0 = b * SCAN_CHUNK + t * 4;
    int s = 0;
#pragma unroll
    for (int k = 0; k < 4; ++k) { const int i = i0 + k; if (i < NN) s += deg[i]; }
#pragma unroll
    for (int m = 32; m >= 1; m >>= 1) s += __shfl_xor(s, m, 64);
    __shared__ int wsum[4];
    if ((t & 63) == 0) wsum[t >> 6] = s;
    __syncthreads();
    if (t == 0) bsum[b] = wsum[0] + wsum[1] + wsum[2] + wsum[3];
}

__global__ void k_scanb(int* __restrict__ bsum) {
    const int t = threadIdx.x;
    __shared__ int sc[128];
    const int v = (t < NBLK) ? bsum[t] : 0;
    sc[t] = v;
    __syncthreads();
    for (int off = 1; off < 128; off <<= 1) {
        int x = 0;
        if (t >= off) x = sc[t - off];
        __syncthreads();
        sc[t] += x;
        __syncthreads();
    }
    if (t < NBLK) bsum[t] = sc[t] - v;   // exclusive
}

__global__ void k_scanfinal(const int* __restrict__ deg, const int* __restrict__ boff,
                            int* __restrict__ rowptr, int* __restrict__ cnt) {
    const int b = blockIdx.x, t = threadIdx.x;
    const int i0 = b * SCAN_CHUNK + t * 4;
    int v[4]; int ts = 0;
#pragma unroll
    for (int k = 0; k < 4; ++k) { const int i = i0 + k; v[k] = (i < NN) ? deg[i] : 0; ts += v[k]; }
    __shared__ int sc[256];
    sc[t] = ts;
    __syncthreads();
    for (int off = 1; off < 256; off <<= 1) {
        int x = 0;
        if (t >= off) x = sc[t - off];
        __syncthreads();
        sc[t] += x;
        __syncthreads();
    }
    int base = boff[b] + (sc[t] - ts);
#pragma unroll
    for (int k = 0; k < 4; ++k) {
        const int i = i0 + k;
        if (i < NN) { rowptr[i] = base; cnt[i] = 0; }
        base += v[k];
    }
    if (b == 0 && t == 0) rowptr[NN] = EE;
}

__global__ void k_scatter(const int* __restrict__ src, const int* __restrict__ dst,
                          const int* __restrict__ rowptr, int* __restrict__ cnt,
                          int* __restrict__ esrc) {
    const int e = blockIdx.x * blockDim.x + threadIdx.x;
    if (e >= EE) return;
    const int d = dst[e];
    const int p = rowptr[d] + atomicAdd(&cnt[d], 1);
    esrc[p] = src[e];
}

// ---------------- fused per-dst GAT layer (single pass, bf16 z, no atomics) ----------------
__global__ void k_gat_dst(const int* __restrict__ rowptr, const int* __restrict__ esrc,
                          const float* __restrict__ el, const float* __restrict__ er,
                          const unsigned short* __restrict__ zb, const float* __restrict__ hin,
                          const float* __restrict__ bg, float* __restrict__ hout) {
    const int j  = threadIdx.x & 63;
    const int wv = threadIdx.x >> 6;
    const int hh = j >> 4;
    const int d = blockIdx.x * 4 + wv;
    if (d >= NN) return;
    const int r0 = rowptr[d], r1 = rowptr[d + 1];
    const float erh = er[d * NH + hh];
    float den = 0.f, sum = 0.f;
    int i = r0;
    for (; i + 8 <= r1; i += 8) {
        int s[8]; float a[8]; float zz[8];
#pragma unroll
        for (int u = 0; u < 8; ++u) s[u] = esrc[i + u];
#pragma unroll
        for (int u = 0; u < 8; ++u) a[u] = el[s[u] * NH + hh];
#pragma unroll
        for (int u = 0; u < 8; ++u) zz[u] = bf2f(zb[(size_t)s[u] * HID + j]);
#pragma unroll
        for (int u = 0; u < 8; ++u) {
            const float w = __expf(lrelu(a[u] + erh));
            den += w;
            sum += w * zz[u];
        }
    }
    for (; i < r1; ++i) {
        const int s = esrc[i];
        const float w = __expf(lrelu(el[s * NH + hh] + erh));
        den += w;
        sum += w * bf2f(zb[(size_t)s * HID + j]);
    }
    float o = hin[(size_t)d * HID + j] + bg[j];
    if (r1 > r0) o += sum / den;
    hout[(size_t)d * HID + j] = o;
}

// LayerNorm + out = hn @ W_out + b_out, 8 rows/wave
__global__ void k_ln_out(const float* __restrict__ h, const float* __restrict__ g,
                         const float* __restrict__ be, const float* __restrict__ Wo,
                         const float* __restrict__ bo, float* __restrict__ out) {
    __shared__ float4 WsT4[HID * OUT_DIM / 4];  // 16 KB transposed+swizzled
    float* WsT = (float*)WsT4;
    for (int idx = threadIdx.x; idx < HID * OUT_DIM; idx += blockDim.x) {
        const int j = idx >> 6, k = idx & 63;
        const int p = (k >> 2) ^ (j & 15);
        WsT[j * HID + p * 4 + (k & 3)] = Wo[k * OUT_DIM + j];
    }
    __syncthreads();
    const int j  = threadIdx.x & 63;
    const int vi = threadIdx.x >> 6;
    const float gj = g[j], bej = be[j], boj = bo[j];
    const float* wrow = WsT + j * HID;
    const int sw = j & 15;
    const int v0 = blockIdx.x * (4 * RB) + vi * RB;
    float hn[RB];
#pragma unroll
    for (int r = 0; r < RB; ++r) {
        const float x = h[(size_t)(v0 + r) * HID + j];
        float s = x;
#pragma unroll
        for (int m = 32; m >= 1; m >>= 1) s += __shfl_xor(s, m, 64);
        const float mu = s * (1.f / 64.f);
        const float dx = x - mu;
        float vs = dx * dx;
#pragma unroll
        for (int m = 32; m >= 1; m >>= 1) vs += __shfl_xor(vs, m, 64);
        hn[r] = dx * rsqrtf(vs * (1.f / 64.f) + LN_EPS) * gj + bej;
    }
    float acc[RB];
#pragma unroll
    for (int r = 0; r < RB; ++r) acc[r] = boj;
#pragma unroll
    for (int c = 0; c < 16; ++c) {
        const float4 wv = *(const float4*)(wrow + ((c ^ sw) << 2));
#pragma unroll
        for (int r = 0; r < RB; ++r) {
            acc[r] += bcast(hn[r], 4 * c + 0) * wv.x;
            acc[r] += bcast(hn[r], 4 * c + 1) * wv.y;
            acc[r] += bcast(hn[r], 4 * c + 2) * wv.z;
            acc[r] += bcast(hn[r], 4 * c + 3) * wv.w;
        }
    }
#pragma unroll
    for (int r = 0; r < RB; ++r) out[(size_t)(v0 + r) * OUT_DIM + j] = acc[r];
}

extern "C" void kernel_launch(void* const* d_in, const int* in_sizes, int n_in,
                              void* d_out, int out_size, void* d_ws, size_t ws_size,
                              hipStream_t stream) {
    const float* X     = (const float*)d_in[0];
    const int*   src   = (const int*)d_in[1];
    const int*   dst   = (const int*)d_in[2];
    const float* W_in  = (const float*)d_in[3];
    const float* b_in  = (const float*)d_in[4];
    // d_in[5..8]: rewiring MLP params — output is dead, skipped entirely
    const float* W_gat = (const float*)d_in[9];   // (L,64,64)
    const float* a_l   = (const float*)d_in[10];  // (L,4,16)
    const float* a_r   = (const float*)d_in[11];
    const float* b_gat = (const float*)d_in[12];  // (L,64)
    const float* ln_g  = (const float*)d_in[13];
    const float* ln_b  = (const float*)d_in[14];
    const float* W_out = (const float*)d_in[15];
    const float* b_out = (const float*)d_in[16];
    float* out = (float*)d_out;

    float* ws = (float*)d_ws;
    float* hA = ws;                                   // N*64 f32
    float* hB = hA + (size_t)NN * HID;                // N*64 f32
    unsigned short* zb = (unsigned short*)(hB + (size_t)NN * HID);  // N*64 bf16
    float* el = (float*)(zb + (size_t)NN * HID);      // N*4
    float* er = el + (size_t)NN * NH;                 // N*4
    int* deg    = (int*)(er + (size_t)NN * NH);       // N ints (reused as cnt)
    int* rowptr = deg + NN;                           // N+1 ints
    int* esrc   = rowptr + NN + 1;                    // E ints
    int* bsum   = esrc + EE;                          // NBLK ints

    const int eg = (EE + 255) / 256;
    const int ng = NN / (4 * RB);   // 3125, exact

    k_in_gemm<<<ng, 256, 0, stream>>>(X, W_in, b_in, hA);

    // CSR by dst (built once, reused for all 3 layers)
    k_zero_deg<<<(NN + 255) / 256, 256, 0, stream>>>(deg);
    k_hist<<<eg, 256, 0, stream>>>(dst, deg);
    k_blocksum<<<NBLK, 256, 0, stream>>>(deg, bsum);
    k_scanb<<<1, 128, 0, stream>>>(bsum);
    k_scanfinal<<<NBLK, 256, 0, stream>>>(deg, bsum, rowptr, deg);
    k_scatter<<<eg, 256, 0, stream>>>(src, dst, rowptr, deg, esrc);

    float* hin = hA;
    float* hout = hB;
    for (int l = 0; l < NL; ++l) {
        k_zgemm<<<ng, 256, 0, stream>>>(hin, W_gat + (size_t)l * HID * HID,
                                        a_l + (size_t)l * HID, a_r + (size_t)l * HID,
                                        zb, el, er);
        k_gat_dst<<<(NN + 3) / 4, 256, 0, stream>>>(rowptr, esrc, el, er, zb, hin,
                                                    b_gat + (size_t)l * HID, hout);
        float* t = hin; hin = hout; hout = t;
    }

    k_ln_out<<<ng, 256, 0, stream>>>(hin, ln_g, ln_b, W_out, b_out, out);
}

// Round 5
// 756.657 us; speedup vs baseline: 3.6698x; 3.6698x over previous
//
#include <hip/hip_runtime.h>

#define NN 100000
#define EE 1600000
#define IN_DIM 128
#define HID 64
#define NH 4
#define DH 16
#define NL 3
#define OUT_DIM 64
#define SLOPE 0.2f
#define LN_EPS 1e-5f
#define RB 4

#define SCAN_CHUNK 1024
#define NBLK ((NN + SCAN_CHUNK - 1) / SCAN_CHUNK)   // 98

__device__ __forceinline__ float lrelu(float x) {
    return x > 0.f ? x : SLOPE * x;
}
__device__ __forceinline__ float bcast(float x, int lane) {
    return __int_as_float(__builtin_amdgcn_readlane(__float_as_int(x), lane));
}
__device__ __forceinline__ unsigned f2bf(float x) {
    unsigned u = __float_as_uint(x);
    u += 0x7FFFu + ((u >> 16) & 1u);      // RNE
    return u >> 16;
}
__device__ __forceinline__ float bf2f(unsigned short b) {
    return __uint_as_float(((unsigned)b) << 16);
}

// h0 = X @ W_in + b_in. W column in registers, rows via readlane broadcast.
__global__ void k_in_gemm(const float* __restrict__ X, const float* __restrict__ W,
                          const float* __restrict__ b, float* __restrict__ h) {
    const int j = threadIdx.x & 63;
    float Wreg[IN_DIM];            // 128 VGPRs, compile-time indexed
#pragma unroll
    for (int k = 0; k < IN_DIM; ++k) Wreg[k] = W[k * HID + j];
    const float bj = b[j];
    const int wid = (blockIdx.x * blockDim.x + threadIdx.x) >> 6;
    const int nw  = (gridDim.x * blockDim.x) >> 6;
    for (int v0 = wid * RB; v0 < NN; v0 += nw * RB) {
        float xlo[RB], xhi[RB];
#pragma unroll
        for (int r = 0; r < RB; ++r) {
            xlo[r] = X[(size_t)(v0 + r) * IN_DIM + j];
            xhi[r] = X[(size_t)(v0 + r) * IN_DIM + 64 + j];
        }
        float acc[RB];
#pragma unroll
        for (int r = 0; r < RB; ++r) acc[r] = bj;
#pragma unroll
        for (int k = 0; k < 64; ++k) {
#pragma unroll
            for (int r = 0; r < RB; ++r)
                acc[r] = fmaf(bcast(xlo[r], k), Wreg[k], acc[r]);
        }
#pragma unroll
        for (int k = 0; k < 64; ++k) {
#pragma unroll
            for (int r = 0; r < RB; ++r)
                acc[r] = fmaf(bcast(xhi[r], k), Wreg[64 + k], acc[r]);
        }
#pragma unroll
        for (int r = 0; r < RB; ++r) h[(size_t)(v0 + r) * HID + j] = acc[r];
    }
}

// z(bf16) = h @ W (64x64) + el/er head reductions. W column in registers.
__global__ void k_zgemm(const float* __restrict__ h, const float* __restrict__ W,
                        const float* __restrict__ al, const float* __restrict__ ar,
                        unsigned* __restrict__ zb32,
                        float* __restrict__ el, float* __restrict__ er) {
    const int j = threadIdx.x & 63;
    float Wreg[HID];               // 64 VGPRs
#pragma unroll
    for (int k = 0; k < HID; ++k) Wreg[k] = W[k * HID + j];
    const float alj = al[j];
    const float arj = ar[j];
    const int head = j >> 4;
    const int wid = (blockIdx.x * blockDim.x + threadIdx.x) >> 6;
    const int nw  = (gridDim.x * blockDim.x) >> 6;
    for (int v0 = wid * RB; v0 < NN; v0 += nw * RB) {
        float hv[RB];
#pragma unroll
        for (int r = 0; r < RB; ++r) hv[r] = h[(size_t)(v0 + r) * HID + j];
        float acc[RB];
#pragma unroll
        for (int r = 0; r < RB; ++r) acc[r] = 0.f;
#pragma unroll
        for (int k = 0; k < HID; ++k) {
#pragma unroll
            for (int r = 0; r < RB; ++r)
                acc[r] = fmaf(bcast(hv[r], k), Wreg[k], acc[r]);
        }
#pragma unroll
        for (int r = 0; r < RB; ++r) {
            // pack bf16 pair -> dword store by even lanes
            const unsigned my = f2bf(acc[r]);
            const unsigned ot = (unsigned)__shfl_xor((int)my, 1, 64);
            if ((j & 1) == 0)
                zb32[(size_t)(v0 + r) * (HID / 2) + (j >> 1)] = my | (ot << 16);
            float pl = acc[r] * alj, pr = acc[r] * arj;
#pragma unroll
            for (int m = 8; m >= 1; m >>= 1) {
                pl += __shfl_xor(pl, m, 64);
                pr += __shfl_xor(pr, m, 64);
            }
            if ((j & 15) == 0) {
                el[(v0 + r) * NH + head] = pl;
                er[(v0 + r) * NH + head] = pr;
            }
        }
    }
}

// ---------------- CSR build (once per launch) ----------------

__global__ void k_zero_deg(int* __restrict__ deg) {
    const int i = blockIdx.x * blockDim.x + threadIdx.x;
    if (i < NN) deg[i] = 0;
}

__global__ void k_hist(const int* __restrict__ dst, int* __restrict__ deg) {
    const int e = blockIdx.x * blockDim.x + threadIdx.x;
    if (e < EE) atomicAdd(&deg[dst[e]], 1);
}

__global__ void k_blocksum(const int* __restrict__ deg, int* __restrict__ bsum) {
    const int b = blockIdx.x, t = threadIdx.x;
    const int i0 = b * SCAN_CHUNK + t * 4;
    int s = 0;
#pragma unroll
    for (int k = 0; k < 4; ++k) { const int i = i0 + k; if (i < NN) s += deg[i]; }
#pragma unroll
    for (int m = 32; m >= 1; m >>= 1) s += __shfl_xor(s, m, 64);
    __shared__ int wsum[4];
    if ((t & 63) == 0) wsum[t >> 6] = s;
    __syncthreads();
    if (t == 0) bsum[b] = wsum[0] + wsum[1] + wsum[2] + wsum[3];
}

__global__ void k_scanb(int* __restrict__ bsum) {
    const int t = threadIdx.x;
    __shared__ int sc[128];
    const int v = (t < NBLK) ? bsum[t] : 0;
    sc[t] = v;
    __syncthreads();
    for (int off = 1; off < 128; off <<= 1) {
        int x = 0;
        if (t >= off) x = sc[t - off];
        __syncthreads();
        sc[t] += x;
        __syncthreads();
    }
    if (t < NBLK) bsum[t] = sc[t] - v;   // exclusive
}

__global__ void k_scanfinal(const int* __restrict__ deg, const int* __restrict__ boff,
                            int* __restrict__ rowptr, int* __restrict__ cnt) {
    const int b = blockIdx.x, t = threadIdx.x;
    const int i0 = b * SCAN_CHUNK + t * 4;
    int v[4]; int ts = 0;
#pragma unroll
    for (int k = 0; k < 4; ++k) { const int i = i0 + k; v[k] = (i < NN) ? deg[i] : 0; ts += v[k]; }
    __shared__ int sc[256];
    sc[t] = ts;
    __syncthreads();
    for (int off = 1; off < 256; off <<= 1) {
        int x = 0;
        if (t >= off) x = sc[t - off];
        __syncthreads();
        sc[t] += x;
        __syncthreads();
    }
    int base = boff[b] + (sc[t] - ts);
#pragma unroll
    for (int k = 0; k < 4; ++k) {
        const int i = i0 + k;
        if (i < NN) { rowptr[i] = base; cnt[i] = 0; }
        base += v[k];
    }
    if (b == 0 && t == 0) rowptr[NN] = EE;
}

__global__ void k_scatter(const int* __restrict__ src, const int* __restrict__ dst,
                          const int* __restrict__ rowptr, int* __restrict__ cnt,
                          int* __restrict__ esrc) {
    const int e = blockIdx.x * blockDim.x + threadIdx.x;
    if (e >= EE) return;
    const int d = dst[e];
    const int p = rowptr[d] + atomicAdd(&cnt[d], 1);
    esrc[p] = src[e];
}

// ---------------- fused per-dst GAT layer (single pass, bf16 z, no atomics) ----------------
__global__ void k_gat_dst(const int* __restrict__ rowptr, const int* __restrict__ esrc,
                          const float* __restrict__ el, const float* __restrict__ er,
                          const unsigned short* __restrict__ zb, const float* __restrict__ hin,
                          const float* __restrict__ bg, float* __restrict__ hout) {
    const int j  = threadIdx.x & 63;
    const int wv = threadIdx.x >> 6;
    const int hh = j >> 4;
    const int d = blockIdx.x * 4 + wv;
    if (d >= NN) return;
    const int r0 = rowptr[d], r1 = rowptr[d + 1];
    const float erh = er[d * NH + hh];
    float den = 0.f, sum = 0.f;
    int i = r0;
    for (; i + 8 <= r1; i += 8) {
        int s[8]; float a[8]; float zz[8];
#pragma unroll
        for (int u = 0; u < 8; ++u) s[u] = esrc[i + u];
#pragma unroll
        for (int u = 0; u < 8; ++u) a[u] = el[s[u] * NH + hh];
#pragma unroll
        for (int u = 0; u < 8; ++u) zz[u] = bf2f(zb[(size_t)s[u] * HID + j]);
#pragma unroll
        for (int u = 0; u < 8; ++u) {
            const float w = __expf(lrelu(a[u] + erh));
            den += w;
            sum += w * zz[u];
        }
    }
    for (; i < r1; ++i) {
        const int s = esrc[i];
        const float w = __expf(lrelu(el[s * NH + hh] + erh));
        den += w;
        sum += w * bf2f(zb[(size_t)s * HID + j]);
    }
    float o = hin[(size_t)d * HID + j] + bg[j];
    if (r1 > r0) o += sum / den;
    hout[(size_t)d * HID + j] = o;
}

// LayerNorm + out = hn @ W_out + b_out. W column in registers.
__global__ void k_ln_out(const float* __restrict__ h, const float* __restrict__ g,
                         const float* __restrict__ be, const float* __restrict__ Wo,
                         const float* __restrict__ bo, float* __restrict__ out) {
    const int j = threadIdx.x & 63;
    float Wreg[HID];
#pragma unroll
    for (int k = 0; k < HID; ++k) Wreg[k] = Wo[k * OUT_DIM + j];
    const float gj = g[j], bej = be[j], boj = bo[j];
    const int wid = (blockIdx.x * blockDim.x + threadIdx.x) >> 6;
    const int nw  = (gridDim.x * blockDim.x) >> 6;
    for (int v0 = wid * RB; v0 < NN; v0 += nw * RB) {
        float hn[RB];
#pragma unroll
        for (int r = 0; r < RB; ++r) {
            const float x = h[(size_t)(v0 + r) * HID + j];
            float s = x;
#pragma unroll
            for (int m = 32; m >= 1; m >>= 1) s += __shfl_xor(s, m, 64);
            const float mu = s * (1.f / 64.f);
            const float dx = x - mu;
            float vs = dx * dx;
#pragma unroll
            for (int m = 32; m >= 1; m >>= 1) vs += __shfl_xor(vs, m, 64);
            hn[r] = dx * rsqrtf(vs * (1.f / 64.f) + LN_EPS) * gj + bej;
        }
        float acc[RB];
#pragma unroll
        for (int r = 0; r < RB; ++r) acc[r] = boj;
#pragma unroll
        for (int k = 0; k < HID; ++k) {
#pragma unroll
            for (int r = 0; r < RB; ++r)
                acc[r] = fmaf(bcast(hn[r], k), Wreg[k], acc[r]);
        }
#pragma unroll
        for (int r = 0; r < RB; ++r) out[(size_t)(v0 + r) * OUT_DIM + j] = acc[r];
    }
}

extern "C" void kernel_launch(void* const* d_in, const int* in_sizes, int n_in,
                              void* d_out, int out_size, void* d_ws, size_t ws_size,
                              hipStream_t stream) {
    const float* X     = (const float*)d_in[0];
    const int*   src   = (const int*)d_in[1];
    const int*   dst   = (const int*)d_in[2];
    const float* W_in  = (const float*)d_in[3];
    const float* b_in  = (const float*)d_in[4];
    // d_in[5..8]: rewiring MLP params — output is dead, skipped entirely
    const float* W_gat = (const float*)d_in[9];   // (L,64,64)
    const float* a_l   = (const float*)d_in[10];  // (L,4,16)
    const float* a_r   = (const float*)d_in[11];
    const float* b_gat = (const float*)d_in[12];  // (L,64)
    const float* ln_g  = (const float*)d_in[13];
    const float* ln_b  = (const float*)d_in[14];
    const float* W_out = (const float*)d_in[15];
    const float* b_out = (const float*)d_in[16];
    float* out = (float*)d_out;

    float* ws = (float*)d_ws;
    float* hA = ws;                                   // N*64 f32
    float* hB = hA + (size_t)NN * HID;                // N*64 f32
    unsigned short* zb = (unsigned short*)(hB + (size_t)NN * HID);  // N*64 bf16
    float* el = (float*)(zb + (size_t)NN * HID);      // N*4
    float* er = el + (size_t)NN * NH;                 // N*4
    int* deg    = (int*)(er + (size_t)NN * NH);       // N ints (reused as cnt)
    int* rowptr = deg + NN;                           // N+1 ints
    int* esrc   = rowptr + NN + 1;                    // E ints
    int* bsum   = esrc + EE;                          // NBLK ints

    const int eg = (EE + 255) / 256;

    k_in_gemm<<<1024, 256, 0, stream>>>(X, W_in, b_in, hA);

    // CSR by dst (built once, reused for all 3 layers)
    k_zero_deg<<<(NN + 255) / 256, 256, 0, stream>>>(deg);
    k_hist<<<eg, 256, 0, stream>>>(dst, deg);
    k_blocksum<<<NBLK, 256, 0, stream>>>(deg, bsum);
    k_scanb<<<1, 128, 0, stream>>>(bsum);
    k_scanfinal<<<NBLK, 256, 0, stream>>>(deg, bsum, rowptr, deg);
    k_scatter<<<eg, 256, 0, stream>>>(src, dst, rowptr, deg, esrc);

    float* hin = hA;
    float* hout = hB;
    for (int l = 0; l < NL; ++l) {
        k_zgemm<<<1024, 256, 0, stream>>>(hin, W_gat + (size_t)l * HID * HID,
                                          a_l + (size_t)l * HID, a_r + (size_t)l * HID,
                                          (unsigned*)zb, el, er);
        k_gat_dst<<<(NN + 3) / 4, 256, 0, stream>>>(rowptr, esrc, el, er, zb, hin,
                                                    b_gat + (size_t)l * HID, hout);
        float* t = hin; hin = hout; hout = t;
    }

    k_ln_out<<<1024, 256, 0, stream>>>(hin, ln_g, ln_b, W_out, b_out, out);
}

// Round 6
// 645.110 us; speedup vs baseline: 4.3043x; 1.1729x over previous
//
#include <hip/hip_runtime.h>

#define NN 100000
#define EE 1600000
#define IN_DIM 128
#define HID 64
#define NH 4
#define DH 16
#define NL 3
#define OUT_DIM 64
#define SLOPE 0.2f
#define LN_EPS 1e-5f
#define RB 4

#define SCAN_CHUNK 1024
#define NBLK ((NN + SCAN_CHUNK - 1) / SCAN_CHUNK)   // 98

__device__ __forceinline__ float lrelu(float x) {
    return x > 0.f ? x : SLOPE * x;
}
__device__ __forceinline__ float bcast(float x, int lane) {
    return __int_as_float(__builtin_amdgcn_readlane(__float_as_int(x), lane));
}
__device__ __forceinline__ unsigned f2bf(float x) {
    unsigned u = __float_as_uint(x);
    u += 0x7FFFu + ((u >> 16) & 1u);      // RNE
    return u >> 16;
}
__device__ __forceinline__ float bf2f(unsigned short b) {
    return __uint_as_float(((unsigned)b) << 16);
}

// h0 = X @ W_in + b_in. W column in registers (needs ~150 VGPR -> launch_bounds(256,2)).
__global__ __launch_bounds__(256, 2)
void k_in_gemm(const float* __restrict__ X, const float* __restrict__ W,
               const float* __restrict__ b, float* __restrict__ h) {
    const int j = threadIdx.x & 63;
    float Wreg[IN_DIM];            // 128 VGPRs, compile-time indexed
#pragma unroll
    for (int k = 0; k < IN_DIM; ++k) Wreg[k] = W[k * HID + j];
    const float bj = b[j];
    const int wid = (blockIdx.x * blockDim.x + threadIdx.x) >> 6;
    const int nw  = (gridDim.x * blockDim.x) >> 6;
    for (int v0 = wid * RB; v0 < NN; v0 += nw * RB) {
        float xlo[RB], xhi[RB];
#pragma unroll
        for (int r = 0; r < RB; ++r) {
            xlo[r] = X[(size_t)(v0 + r) * IN_DIM + j];
            xhi[r] = X[(size_t)(v0 + r) * IN_DIM + 64 + j];
        }
        float acc[RB];
#pragma unroll
        for (int r = 0; r < RB; ++r) acc[r] = bj;
#pragma unroll
        for (int k = 0; k < 64; ++k) {
#pragma unroll
            for (int r = 0; r < RB; ++r)
                acc[r] = fmaf(bcast(xlo[r], k), Wreg[k], acc[r]);
        }
#pragma unroll
        for (int k = 0; k < 64; ++k) {
#pragma unroll
            for (int r = 0; r < RB; ++r)
                acc[r] = fmaf(bcast(xhi[r], k), Wreg[64 + k], acc[r]);
        }
#pragma unroll
        for (int r = 0; r < RB; ++r) h[(size_t)(v0 + r) * HID + j] = acc[r];
    }
}

// z(bf16) = h @ W (64x64) + el/er head reductions. W column in registers (~90 VGPR).
__global__ __launch_bounds__(256, 4)
void k_zgemm(const float* __restrict__ h, const float* __restrict__ W,
             const float* __restrict__ al, const float* __restrict__ ar,
             unsigned* __restrict__ zb32,
             float* __restrict__ el, float* __restrict__ er) {
    const int j = threadIdx.x & 63;
    float Wreg[HID];               // 64 VGPRs
#pragma unroll
    for (int k = 0; k < HID; ++k) Wreg[k] = W[k * HID + j];
    const float alj = al[j];
    const float arj = ar[j];
    const int head = j >> 4;
    const int wid = (blockIdx.x * blockDim.x + threadIdx.x) >> 6;
    const int nw  = (gridDim.x * blockDim.x) >> 6;
    for (int v0 = wid * RB; v0 < NN; v0 += nw * RB) {
        float hv[RB];
#pragma unroll
        for (int r = 0; r < RB; ++r) hv[r] = h[(size_t)(v0 + r) * HID + j];
        float acc[RB];
#pragma unroll
        for (int r = 0; r < RB; ++r) acc[r] = 0.f;
#pragma unroll
        for (int k = 0; k < HID; ++k) {
#pragma unroll
            for (int r = 0; r < RB; ++r)
                acc[r] = fmaf(bcast(hv[r], k), Wreg[k], acc[r]);
        }
#pragma unroll
        for (int r = 0; r < RB; ++r) {
            // pack bf16 pair -> dword store by even lanes
            const unsigned my = f2bf(acc[r]);
            const unsigned ot = (unsigned)__shfl_xor((int)my, 1, 64);
            if ((j & 1) == 0)
                zb32[(size_t)(v0 + r) * (HID / 2) + (j >> 1)] = my | (ot << 16);
            float pl = acc[r] * alj, pr = acc[r] * arj;
#pragma unroll
            for (int m = 8; m >= 1; m >>= 1) {
                pl += __shfl_xor(pl, m, 64);
                pr += __shfl_xor(pr, m, 64);
            }
            if ((j & 15) == 0) {
                el[(v0 + r) * NH + head] = pl;
                er[(v0 + r) * NH + head] = pr;
            }
        }
    }
}

// ---------------- CSR build (once per launch) ----------------

__global__ void k_zero_deg(int* __restrict__ deg) {
    const int i = blockIdx.x * blockDim.x + threadIdx.x;
    if (i < NN) deg[i] = 0;
}

__global__ void k_hist(const int* __restrict__ dst, int* __restrict__ deg) {
    const int e = blockIdx.x * blockDim.x + threadIdx.x;
    if (e < EE) atomicAdd(&deg[dst[e]], 1);
}

__global__ void k_blocksum(const int* __restrict__ deg, int* __restrict__ bsum) {
    const int b = blockIdx.x, t = threadIdx.x;
    const int i0 = b * SCAN_CHUNK + t * 4;
    int s = 0;
#pragma unroll
    for (int k = 0; k < 4; ++k) { const int i = i0 + k; if (i < NN) s += deg[i]; }
#pragma unroll
    for (int m = 32; m >= 1; m >>= 1) s += __shfl_xor(s, m, 64);
    __shared__ int wsum[4];
    if ((t & 63) == 0) wsum[t >> 6] = s;
    __syncthreads();
    if (t == 0) bsum[b] = wsum[0] + wsum[1] + wsum[2] + wsum[3];
}

__global__ void k_scanb(int* __restrict__ bsum) {
    const int t = threadIdx.x;
    __shared__ int sc[128];
    const int v = (t < NBLK) ? bsum[t] : 0;
    sc[t] = v;
    __syncthreads();
    for (int off = 1; off < 128; off <<= 1) {
        int x = 0;
        if (t >= off) x = sc[t - off];
        __syncthreads();
        sc[t] += x;
        __syncthreads();
    }
    if (t < NBLK) bsum[t] = sc[t] - v;   // exclusive
}

__global__ void k_scanfinal(const int* __restrict__ deg, const int* __restrict__ boff,
                            int* __restrict__ rowptr, int* __restrict__ cnt) {
    const int b = blockIdx.x, t = threadIdx.x;
    const int i0 = b * SCAN_CHUNK + t * 4;
    int v[4]; int ts = 0;
#pragma unroll
    for (int k = 0; k < 4; ++k) { const int i = i0 + k; v[k] = (i < NN) ? deg[i] : 0; ts += v[k]; }
    __shared__ int sc[256];
    sc[t] = ts;
    __syncthreads();
    for (int off = 1; off < 256; off <<= 1) {
        int x = 0;
        if (t >= off) x = sc[t - off];
        __syncthreads();
        sc[t] += x;
        __syncthreads();
    }
    int base = boff[b] + (sc[t] - ts);
#pragma unroll
    for (int k = 0; k < 4; ++k) {
        const int i = i0 + k;
        if (i < NN) { rowptr[i] = base; cnt[i] = 0; }
        base += v[k];
    }
    if (b == 0 && t == 0) rowptr[NN] = EE;
}

__global__ void k_scatter(const int* __restrict__ src, const int* __restrict__ dst,
                          const int* __restrict__ rowptr, int* __restrict__ cnt,
                          int* __restrict__ esrc) {
    const int e = blockIdx.x * blockDim.x + threadIdx.x;
    if (e >= EE) return;
    const int d = dst[e];
    const int p = rowptr[d] + atomicAdd(&cnt[d], 1);
    esrc[p] = src[e];
}

// ---------------- fused per-dst GAT layer (single pass, bf16 z, no atomics) ----------------
__global__ void k_gat_dst(const int* __restrict__ rowptr, const int* __restrict__ esrc,
                          const float* __restrict__ el, const float* __restrict__ er,
                          const unsigned short* __restrict__ zb, const float* __restrict__ hin,
                          const float* __restrict__ bg, float* __restrict__ hout) {
    const int j  = threadIdx.x & 63;
    const int wv = threadIdx.x >> 6;
    const int hh = j >> 4;
    const int d = blockIdx.x * 4 + wv;
    if (d >= NN) return;
    const int r0 = rowptr[d], r1 = rowptr[d + 1];
    const float erh = er[d * NH + hh];
    float den = 0.f, sum = 0.f;
    int i = r0;
    for (; i + 8 <= r1; i += 8) {
        int s[8]; float a[8]; float zz[8];
#pragma unroll
        for (int u = 0; u < 8; ++u) s[u] = esrc[i + u];
#pragma unroll
        for (int u = 0; u < 8; ++u) a[u] = el[s[u] * NH + hh];
#pragma unroll
        for (int u = 0; u < 8; ++u) zz[u] = bf2f(zb[(size_t)s[u] * HID + j]);
#pragma unroll
        for (int u = 0; u < 8; ++u) {
            const float w = __expf(lrelu(a[u] + erh));
            den += w;
            sum += w * zz[u];
        }
    }
    for (; i < r1; ++i) {
        const int s = esrc[i];
        const float w = __expf(lrelu(el[s * NH + hh] + erh));
        den += w;
        sum += w * bf2f(zb[(size_t)s * HID + j]);
    }
    float o = hin[(size_t)d * HID + j] + bg[j];
    if (r1 > r0) o += sum / den;
    hout[(size_t)d * HID + j] = o;
}

// LayerNorm + out = hn @ W_out + b_out. W column in registers (~90 VGPR).
__global__ __launch_bounds__(256, 4)
void k_ln_out(const float* __restrict__ h, const float* __restrict__ g,
              const float* __restrict__ be, const float* __restrict__ Wo,
              const float* __restrict__ bo, float* __restrict__ out) {
    const int j = threadIdx.x & 63;
    float Wreg[HID];
#pragma unroll
    for (int k = 0; k < HID; ++k) Wreg[k] = Wo[k * OUT_DIM + j];
    const float gj = g[j], bej = be[j], boj = bo[j];
    const int wid = (blockIdx.x * blockDim.x + threadIdx.x) >> 6;
    const int nw  = (gridDim.x * blockDim.x) >> 6;
    for (int v0 = wid * RB; v0 < NN; v0 += nw * RB) {
        float hn[RB];
#pragma unroll
        for (int r = 0; r < RB; ++r) {
            const float x = h[(size_t)(v0 + r) * HID + j];
            float s = x;
#pragma unroll
            for (int m = 32; m >= 1; m >>= 1) s += __shfl_xor(s, m, 64);
            const float mu = s * (1.f / 64.f);
            const float dx = x - mu;
            float vs = dx * dx;
#pragma unroll
            for (int m = 32; m >= 1; m >>= 1) vs += __shfl_xor(vs, m, 64);
            hn[r] = dx * rsqrtf(vs * (1.f / 64.f) + LN_EPS) * gj + bej;
        }
        float acc[RB];
#pragma unroll
        for (int r = 0; r < RB; ++r) acc[r] = boj;
#pragma unroll
        for (int k = 0; k < HID; ++k) {
#pragma unroll
            for (int r = 0; r < RB; ++r)
                acc[r] = fmaf(bcast(hn[r], k), Wreg[k], acc[r]);
        }
#pragma unroll
        for (int r = 0; r < RB; ++r) out[(size_t)(v0 + r) * OUT_DIM + j] = acc[r];
    }
}

extern "C" void kernel_launch(void* const* d_in, const int* in_sizes, int n_in,
                              void* d_out, int out_size, void* d_ws, size_t ws_size,
                              hipStream_t stream) {
    const float* X     = (const float*)d_in[0];
    const int*   src   = (const int*)d_in[1];
    const int*   dst   = (const int*)d_in[2];
    const float* W_in  = (const float*)d_in[3];
    const float* b_in  = (const float*)d_in[4];
    // d_in[5..8]: rewiring MLP params — output is dead, skipped entirely
    const float* W_gat = (const float*)d_in[9];   // (L,64,64)
    const float* a_l   = (const float*)d_in[10];  // (L,4,16)
    const float* a_r   = (const float*)d_in[11];
    const float* b_gat = (const float*)d_in[12];  // (L,64)
    const float* ln_g  = (const float*)d_in[13];
    const float* ln_b  = (const float*)d_in[14];
    const float* W_out = (const float*)d_in[15];
    const float* b_out = (const float*)d_in[16];
    float* out = (float*)d_out;

    float* ws = (float*)d_ws;
    float* hA = ws;                                   // N*64 f32
    float* hB = hA + (size_t)NN * HID;                // N*64 f32
    unsigned short* zb = (unsigned short*)(hB + (size_t)NN * HID);  // N*64 bf16
    float* el = (float*)(zb + (size_t)NN * HID);      // N*4
    float* er = el + (size_t)NN * NH;                 // N*4
    int* deg    = (int*)(er + (size_t)NN * NH);       // N ints (reused as cnt)
    int* rowptr = deg + NN;                           // N+1 ints
    int* esrc   = rowptr + NN + 1;                    // E ints
    int* bsum   = esrc + EE;                          // NBLK ints

    const int eg = (EE + 255) / 256;

    k_in_gemm<<<1024, 256, 0, stream>>>(X, W_in, b_in, hA);

    // CSR by dst (built once, reused for all 3 layers)
    k_zero_deg<<<(NN + 255) / 256, 256, 0, stream>>>(deg);
    k_hist<<<eg, 256, 0, stream>>>(dst, deg);
    k_blocksum<<<NBLK, 256, 0, stream>>>(deg, bsum);
    k_scanb<<<1, 128, 0, stream>>>(bsum);
    k_scanfinal<<<NBLK, 256, 0, stream>>>(deg, bsum, rowptr, deg);
    k_scatter<<<eg, 256, 0, stream>>>(src, dst, rowptr, deg, esrc);

    float* hin = hA;
    float* hout = hB;
    for (int l = 0; l < NL; ++l) {
        k_zgemm<<<1024, 256, 0, stream>>>(hin, W_gat + (size_t)l * HID * HID,
                                          a_l + (size_t)l * HID, a_r + (size_t)l * HID,
                                          (unsigned*)zb, el, er);
        k_gat_dst<<<(NN + 3) / 4, 256, 0, stream>>>(rowptr, esrc, el, er, zb, hin,
                                                    b_gat + (size_t)l * HID, hout);
        float* t = hin; hin = hout; hout = t;
    }

    k_ln_out<<<1024, 256, 0, stream>>>(hin, ln_g, ln_b, W_out, b_out, out);
}

// Round 7
// 509.709 us; speedup vs baseline: 5.4477x; 1.2656x over previous
//
#include <hip/hip_runtime.h>

#define NN 100000
#define EE 1600000
#define IN_DIM 128
#define HID 64
#define NH 4
#define DH 16
#define NL 3
#define OUT_DIM 64
#define SLOPE 0.2f
#define LN_EPS 1e-5f
#define RB 4

// bucket CSR build
#define BSH 9
#define BSZ 512                               // nodes per bucket
#define NB ((NN + BSZ - 1) / BSZ)             // 196
#define CAP 10240                             // per-bucket capacity (avg 8163)
#define CHUNK 4096
#define P1_BLOCKS ((EE + CHUNK - 1) / CHUNK)  // 391

__device__ __forceinline__ float lrelu(float x) {
    return x > 0.f ? x : SLOPE * x;
}
__device__ __forceinline__ float bcast(float x, int lane) {
    return __int_as_float(__builtin_amdgcn_readlane(__float_as_int(x), lane));
}
__device__ __forceinline__ unsigned f2bf(float x) {
    unsigned u = __float_as_uint(x);
    u += 0x7FFFu + ((u >> 16) & 1u);      // RNE
    return u >> 16;
}
__device__ __forceinline__ float bf2f(unsigned short b) {
    return __uint_as_float(((unsigned)b) << 16);
}

// h0 = X @ W_in + b_in. W column in registers.
__global__ __launch_bounds__(256, 2)
void k_in_gemm(const float* __restrict__ X, const float* __restrict__ W,
               const float* __restrict__ b, float* __restrict__ h) {
    const int j = threadIdx.x & 63;
    float Wreg[IN_DIM];
#pragma unroll
    for (int k = 0; k < IN_DIM; ++k) Wreg[k] = W[k * HID + j];
    const float bj = b[j];
    const int wid = (blockIdx.x * blockDim.x + threadIdx.x) >> 6;
    const int nw  = (gridDim.x * blockDim.x) >> 6;
    for (int v0 = wid * RB; v0 < NN; v0 += nw * RB) {
        float xlo[RB], xhi[RB];
#pragma unroll
        for (int r = 0; r < RB; ++r) {
            xlo[r] = X[(size_t)(v0 + r) * IN_DIM + j];
            xhi[r] = X[(size_t)(v0 + r) * IN_DIM + 64 + j];
        }
        float acc[RB];
#pragma unroll
        for (int r = 0; r < RB; ++r) acc[r] = bj;
#pragma unroll
        for (int k = 0; k < 64; ++k) {
#pragma unroll
            for (int r = 0; r < RB; ++r)
                acc[r] = fmaf(bcast(xlo[r], k), Wreg[k], acc[r]);
        }
#pragma unroll
        for (int k = 0; k < 64; ++k) {
#pragma unroll
            for (int r = 0; r < RB; ++r)
                acc[r] = fmaf(bcast(xhi[r], k), Wreg[64 + k], acc[r]);
        }
#pragma unroll
        for (int r = 0; r < RB; ++r) h[(size_t)(v0 + r) * HID + j] = acc[r];
    }
}

// z(bf16) = h @ W (64x64) + el/er head reductions. W column in registers.
__global__ __launch_bounds__(256, 4)
void k_zgemm(const float* __restrict__ h, const float* __restrict__ W,
             const float* __restrict__ al, const float* __restrict__ ar,
             unsigned* __restrict__ zb32,
             float* __restrict__ el, float* __restrict__ er) {
    const int j = threadIdx.x & 63;
    float Wreg[HID];
#pragma unroll
    for (int k = 0; k < HID; ++k) Wreg[k] = W[k * HID + j];
    const float alj = al[j];
    const float arj = ar[j];
    const int head = j >> 4;
    const int wid = (blockIdx.x * blockDim.x + threadIdx.x) >> 6;
    const int nw  = (gridDim.x * blockDim.x) >> 6;
    for (int v0 = wid * RB; v0 < NN; v0 += nw * RB) {
        float hv[RB];
#pragma unroll
        for (int r = 0; r < RB; ++r) hv[r] = h[(size_t)(v0 + r) * HID + j];
        float acc[RB];
#pragma unroll
        for (int r = 0; r < RB; ++r) acc[r] = 0.f;
#pragma unroll
        for (int k = 0; k < HID; ++k) {
#pragma unroll
            for (int r = 0; r < RB; ++r)
                acc[r] = fmaf(bcast(hv[r], k), Wreg[k], acc[r]);
        }
#pragma unroll
        for (int r = 0; r < RB; ++r) {
            const unsigned my = f2bf(acc[r]);
            const unsigned ot = (unsigned)__shfl_xor((int)my, 1, 64);
            if ((j & 1) == 0)
                zb32[(size_t)(v0 + r) * (HID / 2) + (j >> 1)] = my | (ot << 16);
            float pl = acc[r] * alj, pr = acc[r] * arj;
#pragma unroll
            for (int m = 8; m >= 1; m >>= 1) {
                pl += __shfl_xor(pl, m, 64);
                pr += __shfl_xor(pr, m, 64);
            }
            if ((j & 15) == 0) {
                el[(v0 + r) * NH + head] = pl;
                er[(v0 + r) * NH + head] = pr;
            }
        }
    }
}

// ---------------- bucket-sort CSR build ----------------

__global__ void k_zero_bcnt(int* __restrict__ bcnt) {
    if (threadIdx.x < NB) bcnt[threadIdx.x] = 0;
}

// Pass 1: block-local counting sort by bucket (d>>9), contiguous copy-out.
__global__ __launch_bounds__(256)
void k_bucketize(const int* __restrict__ src, const int* __restrict__ dst,
                 int* __restrict__ bcnt, int2* __restrict__ bbuf) {
    __shared__ int lh[256];      // hist -> running counter
    __shared__ int lbase[256];   // exclusive prefix
    __shared__ int lcnt[256];    // saved counts
    __shared__ int gbase[256];
    __shared__ int sc[256];
    __shared__ int2 stage[CHUNK];  // 32 KB
    const int t = threadIdx.x;
    const int e0 = blockIdx.x * CHUNK;
    const int n = min(CHUNK, EE - e0);
    lh[t] = 0;
    __syncthreads();
    int myd[CHUNK / 256], mys[CHUNK / 256];
#pragma unroll
    for (int i = 0; i < CHUNK / 256; ++i) {
        const int o = i * 256 + t;
        if (o < n) {
            myd[i] = dst[e0 + o];
            mys[i] = src[e0 + o];
            atomicAdd(&lh[myd[i] >> BSH], 1);
        } else myd[i] = -1;
    }
    __syncthreads();
    {   // exclusive scan of lh
        const int v = lh[t];
        lcnt[t] = v;
        sc[t] = v;
        __syncthreads();
        for (int off = 1; off < 256; off <<= 1) {
            const int x = (t >= off) ? sc[t - off] : 0;
            __syncthreads();
            sc[t] += x;
            __syncthreads();
        }
        lbase[t] = sc[t] - v;
        lh[t] = sc[t] - v;     // running counter
    }
    __syncthreads();
#pragma unroll
    for (int i = 0; i < CHUNK / 256; ++i) {
        if (myd[i] >= 0) {
            const int b = myd[i] >> BSH;
            const int p = atomicAdd(&lh[b], 1);
            stage[p] = make_int2(mys[i], myd[i]);
        }
    }
    __syncthreads();
    if (t < NB && lcnt[t] > 0) gbase[t] = atomicAdd(&bcnt[t], lcnt[t]);
    __syncthreads();
    for (int i = t; i < n; i += 256) {
        const int2 en = stage[i];
        const int b = en.y >> BSH;
        const int gp = gbase[b] + (i - lbase[b]);
        if (gp < CAP) bbuf[(size_t)b * CAP + gp] = en;
    }
}

// Pass 1.5: exclusive scan of the 196 bucket counts.
__global__ void k_bscan(const int* __restrict__ bcnt, int* __restrict__ bbase,
                        int* __restrict__ rowptr) {
    const int t = threadIdx.x;
    __shared__ int sc[256];
    const int v = (t < NB) ? bcnt[t] : 0;
    sc[t] = v;
    __syncthreads();
    for (int off = 1; off < 256; off <<= 1) {
        const int x = (t >= off) ? sc[t - off] : 0;
        __syncthreads();
        sc[t] += x;
        __syncthreads();
    }
    if (t < NB) bbase[t] = sc[t] - v;
    if (t == 0) rowptr[NN] = EE;
}

// Pass 2: one block per bucket — local hist+scan over 512 nodes,
// coalesced rowptr write, esrc scatter confined to this block's region.
__global__ __launch_bounds__(256)
void k_localcsr(const int* __restrict__ bcnt, const int* __restrict__ bbase,
                const int2* __restrict__ bbuf, int* __restrict__ rowptr,
                int* __restrict__ esrc) {
    const int b = blockIdx.x;
    const int t = threadIdx.x;
    const int cnt = bcnt[b];
    const int base = bbase[b];
    const int n0 = b * BSZ;
    const int nn = min(BSZ, NN - n0);
    __shared__ int lh[BSZ];
    __shared__ int lsc[BSZ];
    __shared__ int sc[256];
    for (int i = t; i < BSZ; i += 256) lh[i] = 0;
    __syncthreads();
    const int2* bb = bbuf + (size_t)b * CAP;
    for (int i = t; i < cnt; i += 256) atomicAdd(&lh[bb[i].y & (BSZ - 1)], 1);
    __syncthreads();
    const int a0 = lh[2 * t], a1 = lh[2 * t + 1];
    const int ts = a0 + a1;
    sc[t] = ts;
    __syncthreads();
    for (int off = 1; off < 256; off <<= 1) {
        const int x = (t >= off) ? sc[t - off] : 0;
        __syncthreads();
        sc[t] += x;
        __syncthreads();
    }
    const int ebase = sc[t] - ts;
    lsc[2 * t] = ebase;
    lsc[2 * t + 1] = ebase + a0;
    __syncthreads();
    for (int i = t; i < BSZ; i += 256) {
        if (i < nn) rowptr[n0 + i] = base + lsc[i];
        lh[i] = lsc[i];        // running counters
    }
    __syncthreads();
    for (int i = t; i < cnt; i += 256) {
        const int2 en = bb[i];
        const int p = atomicAdd(&lh[en.y & (BSZ - 1)], 1);
        esrc[base + p] = en.x;
    }
}

// ---------------- fused per-dst GAT layer (single pass, bf16 z, no atomics) ----------------
__global__ void k_gat_dst(const int* __restrict__ rowptr, const int* __restrict__ esrc,
                          const float* __restrict__ el, const float* __restrict__ er,
                          const unsigned short* __restrict__ zb, const float* __restrict__ hin,
                          const float* __restrict__ bg, float* __restrict__ hout) {
    const int j  = threadIdx.x & 63;
    const int wv = threadIdx.x >> 6;
    const int hh = j >> 4;
    const int d = blockIdx.x * 4 + wv;
    if (d >= NN) return;
    const int r0 = rowptr[d], r1 = rowptr[d + 1];
    const float erh = er[d * NH + hh];
    float den = 0.f, sum = 0.f;
    int i = r0;
    for (; i + 8 <= r1; i += 8) {
        int s[8]; float a[8]; float zz[8];
#pragma unroll
        for (int u = 0; u < 8; ++u) s[u] = esrc[i + u];
#pragma unroll
        for (int u = 0; u < 8; ++u) a[u] = el[s[u] * NH + hh];
#pragma unroll
        for (int u = 0; u < 8; ++u) zz[u] = bf2f(zb[(size_t)s[u] * HID + j]);
#pragma unroll
        for (int u = 0; u < 8; ++u) {
            const float w = __expf(lrelu(a[u] + erh));
            den += w;
            sum += w * zz[u];
        }
    }
    for (; i < r1; ++i) {
        const int s = esrc[i];
        const float w = __expf(lrelu(el[s * NH + hh] + erh));
        den += w;
        sum += w * bf2f(zb[(size_t)s * HID + j]);
    }
    float o = hin[(size_t)d * HID + j] + bg[j];
    if (r1 > r0) o += sum / den;
    hout[(size_t)d * HID + j] = o;
}

// LayerNorm + out = hn @ W_out + b_out. W column in registers.
__global__ __launch_bounds__(256, 4)
void k_ln_out(const float* __restrict__ h, const float* __restrict__ g,
              const float* __restrict__ be, const float* __restrict__ Wo,
              const float* __restrict__ bo, float* __restrict__ out) {
    const int j = threadIdx.x & 63;
    float Wreg[HID];
#pragma unroll
    for (int k = 0; k < HID; ++k) Wreg[k] = Wo[k * OUT_DIM + j];
    const float gj = g[j], bej = be[j], boj = bo[j];
    const int wid = (blockIdx.x * blockDim.x + threadIdx.x) >> 6;
    const int nw  = (gridDim.x * blockDim.x) >> 6;
    for (int v0 = wid * RB; v0 < NN; v0 += nw * RB) {
        float hn[RB];
#pragma unroll
        for (int r = 0; r < RB; ++r) {
            const float x = h[(size_t)(v0 + r) * HID + j];
            float s = x;
#pragma unroll
            for (int m = 32; m >= 1; m >>= 1) s += __shfl_xor(s, m, 64);
            const float mu = s * (1.f / 64.f);
            const float dx = x - mu;
            float vs = dx * dx;
#pragma unroll
            for (int m = 32; m >= 1; m >>= 1) vs += __shfl_xor(vs, m, 64);
            hn[r] = dx * rsqrtf(vs * (1.f / 64.f) + LN_EPS) * gj + bej;
        }
        float acc[RB];
#pragma unroll
        for (int r = 0; r < RB; ++r) acc[r] = boj;
#pragma unroll
        for (int k = 0; k < HID; ++k) {
#pragma unroll
            for (int r = 0; r < RB; ++r)
                acc[r] = fmaf(bcast(hn[r], k), Wreg[k], acc[r]);
        }
#pragma unroll
        for (int r = 0; r < RB; ++r) out[(size_t)(v0 + r) * OUT_DIM + j] = acc[r];
    }
}

extern "C" void kernel_launch(void* const* d_in, const int* in_sizes, int n_in,
                              void* d_out, int out_size, void* d_ws, size_t ws_size,
                              hipStream_t stream) {
    const float* X     = (const float*)d_in[0];
    const int*   src   = (const int*)d_in[1];
    const int*   dst   = (const int*)d_in[2];
    const float* W_in  = (const float*)d_in[3];
    const float* b_in  = (const float*)d_in[4];
    // d_in[5..8]: rewiring MLP params — output is dead, skipped entirely
    const float* W_gat = (const float*)d_in[9];   // (L,64,64)
    const float* a_l   = (const float*)d_in[10];  // (L,4,16)
    const float* a_r   = (const float*)d_in[11];
    const float* b_gat = (const float*)d_in[12];  // (L,64)
    const float* ln_g  = (const float*)d_in[13];
    const float* ln_b  = (const float*)d_in[14];
    const float* W_out = (const float*)d_in[15];
    const float* b_out = (const float*)d_in[16];
    float* out = (float*)d_out;

    float* ws = (float*)d_ws;
    float* hA = ws;                                   // N*64 f32
    float* hB = hA + (size_t)NN * HID;                // N*64 f32
    unsigned short* zb = (unsigned short*)(hB + (size_t)NN * HID);  // N*64 bf16
    float* el = (float*)(zb + (size_t)NN * HID);      // N*4
    float* er = el + (size_t)NN * NH;                 // N*4
    int* rowptr = (int*)(er + (size_t)NN * NH);       // N+1 ints
    int* esrc   = rowptr + NN + 1;                    // E ints
    int* bcnt   = esrc + EE;                          // NB ints
    int* bbase  = bcnt + NB;                          // NB ints
    int2* bbuf  = (int2*)hB;  // 16.1 MB, aliases hB (dead until first k_gat_dst)

    k_in_gemm<<<1024, 256, 0, stream>>>(X, W_in, b_in, hA);

    // bucket-sort CSR by dst (built once, reused for all 3 layers)
    k_zero_bcnt<<<1, 256, 0, stream>>>(bcnt);
    k_bucketize<<<P1_BLOCKS, 256, 0, stream>>>(src, dst, bcnt, bbuf);
    k_bscan<<<1, 256, 0, stream>>>(bcnt, bbase, rowptr);
    k_localcsr<<<NB, 256, 0, stream>>>(bcnt, bbase, bbuf, rowptr, esrc);

    float* hin = hA;
    float* hout = hB;
    for (int l = 0; l < NL; ++l) {
        k_zgemm<<<1024, 256, 0, stream>>>(hin, W_gat + (size_t)l * HID * HID,
                                          a_l + (size_t)l * HID, a_r + (size_t)l * HID,
                                          (unsigned*)zb, el, er);
        k_gat_dst<<<(NN + 3) / 4, 256, 0, stream>>>(rowptr, esrc, el, er, zb, hin,
                                                    b_gat + (size_t)l * HID, hout);
        float* t = hin; hin = hout; hout = t;
    }

    k_ln_out<<<1024, 256, 0, stream>>>(hin, ln_g, ln_b, W_out, b_out, out);
}